// Round 12
// baseline (1022.897 us; speedup 1.0000x reference)
//
#include <hip/hip_runtime.h>
#include <hip/hip_bf16.h>
#include <math.h>

#define NGENES 19836
#define BATCH 8
#define DIN 11
#define DH 64
#define NNODES (BATCH * NGENES)        /* 158688 */
#define E_PER (NGENES * 16)            /* 317376 edges per graph */
#define NEDGES (NNODES * 16)           /* 2539008 */
#define NDH (NNODES * DH)              /* 10156032 */
#define NBLK_NODE ((NNODES + 255) / 256)  /* 620 */

#define SCAN_CHUNK 1024
#define NSBLK ((NNODES + SCAN_CHUNK - 1) / SCAN_CHUNK)  /* 155 */

/* output layout (floats): preds[8], w[NNODES], sae_loss[1], dec[NNODES*64] */
#define OUT_PREDS 0
#define OUT_W 8
#define OUT_SAE (8 + NNODES)
#define OUT_DEC (9 + NNODES)

__device__ __forceinline__ float gelu_f(float x) {
    return 0.5f * x * (1.0f + erff(x * 0.70710678118654752f));
}

__device__ __forceinline__ float bcast(float v, int lane) {
    return __int_as_float(__builtin_amdgcn_readlane(__float_as_int(v), lane));
}

__device__ __forceinline__ float wave_sum(float v) {
    #pragma unroll
    for (int o = 32; o; o >>= 1) v += __shfl_xor(v, o, 64);
    return v;
}

/* K1: h16 = bf16(gelu(x @ enc_W.T + enc_b) + gene_emb[gene]); XCD-affine graph = blockIdx%8 */
__global__ void k_encoder(const float* __restrict__ x, const float* __restrict__ encW,
                          const float* __restrict__ encB, const float* __restrict__ gemb,
                          __hip_bfloat16* __restrict__ h16) {
    int lane = threadIdx.x & 63;
    int g = blockIdx.x & 7;
    int wix = (blockIdx.x >> 3) * (blockDim.x >> 6) + (threadIdx.x >> 6);
    int wper = (gridDim.x >> 3) * (blockDim.x >> 6);
    float wreg[DIN];
    #pragma unroll
    for (int k = 0; k < DIN; ++k) wreg[k] = encW[lane * DIN + k];
    float bias = encB[lane];
    size_t gb = (size_t)g * NGENES;
    for (int i = wix; i < NGENES; i += wper) {
        size_t node = gb + i;
        const float* xr = x + node * DIN;
        float acc = bias;
        #pragma unroll
        for (int k = 0; k < DIN; ++k) acc = fmaf(xr[k], wreg[k], acc);
        float hv = gelu_f(acc) + gemb[(size_t)i * DH + lane];
        h16[node * DH + lane] = __float2bfloat16(hv);
    }
}

/* CSR histogram, XCD-local per graph */
__global__ void k_hist(const int* __restrict__ dst, int* __restrict__ counts) {
    int g = blockIdx.x & 7;
    int t = (blockIdx.x >> 3) * blockDim.x + threadIdx.x;
    int nt = (gridDim.x >> 3) * blockDim.x;
    const int* dg = dst + (size_t)g * E_PER;
    for (int e = t; e < E_PER; e += nt)
        atomicAdd(&counts[dg[e]], 1);
}

/* scan pass 1: per-block sums */
__global__ void k_scan1(const int* __restrict__ counts, int* __restrict__ bsum) {
    __shared__ int red[256];
    int base = blockIdx.x * SCAN_CHUNK + threadIdx.x * 4;
    int s = 0;
    #pragma unroll
    for (int i = 0; i < 4; ++i) {
        int n = base + i;
        if (n < NNODES) s += counts[n];
    }
    red[threadIdx.x] = s;
    __syncthreads();
    for (int o = 128; o; o >>= 1) {
        if (threadIdx.x < o) red[threadIdx.x] += red[threadIdx.x + o];
        __syncthreads();
    }
    if (threadIdx.x == 0) bsum[blockIdx.x] = red[0];
}

/* scan pass 2: exclusive scan of block sums */
__global__ void k_scan2(const int* __restrict__ bsum, int* __restrict__ boff) {
    __shared__ int red[256];
    int t = threadIdx.x;
    int v = (t < NSBLK) ? bsum[t] : 0;
    red[t] = v;
    __syncthreads();
    for (int o = 1; o < 256; o <<= 1) {
        int u = (t >= o) ? red[t - o] : 0;
        __syncthreads();
        red[t] += u;
        __syncthreads();
    }
    if (t < NSBLK) boff[t] = red[t] - v;
}

/* scan pass 3: intra-block exclusive scan -> offsets, cursor */
__global__ void k_scan3(const int* __restrict__ counts, const int* __restrict__ boff,
                        int* __restrict__ offsets, int* __restrict__ cursor) {
    __shared__ int red[256];
    int t = threadIdx.x;
    int base = blockIdx.x * SCAN_CHUNK + t * 4;
    int c[4];
    int s = 0;
    #pragma unroll
    for (int i = 0; i < 4; ++i) {
        int n = base + i;
        c[i] = (n < NNODES) ? counts[n] : 0;
        s += c[i];
    }
    red[t] = s;
    __syncthreads();
    for (int o = 1; o < 256; o <<= 1) {
        int v = (t >= o) ? red[t - o] : 0;
        __syncthreads();
        red[t] += v;
        __syncthreads();
    }
    int excl = red[t] - s + boff[blockIdx.x];
    #pragma unroll
    for (int i = 0; i < 4; ++i) {
        int n = base + i;
        if (n < NNODES) { offsets[n] = excl; cursor[n] = excl; }
        excl += c[i];
    }
}

/* scatter edges into CSR (local src ids), XCD-local per graph */
__global__ void k_scatter(const int* __restrict__ src, const int* __restrict__ dst,
                          int* __restrict__ cursor, unsigned short* __restrict__ csr) {
    int g = blockIdx.x & 7;
    int t = (blockIdx.x >> 3) * blockDim.x + threadIdx.x;
    int nt = (gridDim.x >> 3) * blockDim.x;
    const int* sg = src + (size_t)g * E_PER;
    const int* dg = dst + (size_t)g * E_PER;
    int gbase = g * NGENES;
    for (int e = t; e < E_PER; e += nt) {
        int p = atomicAdd(&cursor[dg[e]], 1);
        csr[p] = (unsigned short)(sg[e] - gbase);
    }
}

/* gather only: t[node][dim] = bf16(h_self + sum_neigh h); XCD-affine; no LDS */
__global__ void __launch_bounds__(256, 4)
k_agg(const __hip_bfloat16* __restrict__ h16, const int* __restrict__ offsets,
      const int* __restrict__ counts, const unsigned short* __restrict__ csr,
      __hip_bfloat16* __restrict__ t) {
    int lane = threadIdx.x & 63;
    int g = blockIdx.x & 7;
    int wix = (blockIdx.x >> 3) * 4 + (threadIdx.x >> 6);
    int wper = (gridDim.x >> 3) * 4;
    int gbase = g * NGENES;
    for (int i = wix; i < NGENES; i += wper) {
        int node = gbase + i;
        float a[8];
        a[0] = __bfloat162float(h16[(size_t)node * DH + lane]);
        #pragma unroll
        for (int u = 1; u < 8; ++u) a[u] = 0.f;
        int start = offsets[node];
        int cnt = counts[node];
        for (int e0 = 0; e0 < cnt; e0 += 64) {
            int nn = min(64, cnt - e0);
            int iv = (lane < nn) ? (int)csr[start + e0 + lane] : 0;
            int j = 0;
            for (; j + 7 < nn; j += 8) {
                #pragma unroll
                for (int u = 0; u < 8; ++u) {
                    int v = gbase + __shfl(iv, j + u, 64);
                    a[u] += __bfloat162float(h16[(size_t)v * DH + lane]);
                }
            }
            for (; j < nn; ++j)
                a[0] += __bfloat162float(h16[(size_t)(gbase + __shfl(iv, j, 64)) * DH + lane]);
        }
        float tval = ((a[0] + a[1]) + (a[2] + a[3])) + ((a[4] + a[5]) + (a[6] + a[7]));
        t[(size_t)node * DH + lane] = __float2bfloat16(tval);
    }
}

/* GIN matmul, thread-per-node: tr[64] regs <- t row; h2_t[d][n] = ginW@tr (coalesced);
   BN stats via per-wave wave_sum -> LDS -> one atomic per block per dim */
__global__ void __launch_bounds__(256, 4)
k_gin(const __hip_bfloat16* __restrict__ t, const float* __restrict__ ginW,
      float* __restrict__ h2t, float* __restrict__ stats) {
    __shared__ float ws[4][2][DH];
    int lane = threadIdx.x & 63;
    int w = threadIdx.x >> 6;
    int node = blockIdx.x * 256 + threadIdx.x;
    bool act = node < NNODES;
    int nc = act ? node : 0;
    const __hip_bfloat16* rp = t + (size_t)nc * DH;
    float tr[DH];
    #pragma unroll
    for (int j = 0; j < 8; ++j) {
        uint4 v = *reinterpret_cast<const uint4*>(rp + j * 8);
        tr[j * 8 + 0] = __int_as_float(v.x << 16);
        tr[j * 8 + 1] = __int_as_float(v.x & 0xffff0000u);
        tr[j * 8 + 2] = __int_as_float(v.y << 16);
        tr[j * 8 + 3] = __int_as_float(v.y & 0xffff0000u);
        tr[j * 8 + 4] = __int_as_float(v.z << 16);
        tr[j * 8 + 5] = __int_as_float(v.z & 0xffff0000u);
        tr[j * 8 + 6] = __int_as_float(v.w << 16);
        tr[j * 8 + 7] = __int_as_float(v.w & 0xffff0000u);
    }
    #pragma unroll 1
    for (int d4 = 0; d4 < DH; d4 += 4) {
        float s0 = 0.f, s1 = 0.f, s2 = 0.f, s3 = 0.f;
        #pragma unroll
        for (int k = 0; k < DH; ++k) {
            float tk = tr[k];
            s0 = fmaf(ginW[(d4 + 0) * DH + k], tk, s0);
            s1 = fmaf(ginW[(d4 + 1) * DH + k], tk, s1);
            s2 = fmaf(ginW[(d4 + 2) * DH + k], tk, s2);
            s3 = fmaf(ginW[(d4 + 3) * DH + k], tk, s3);
        }
        if (act) {
            h2t[(size_t)(d4 + 0) * NNODES + node] = s0;
            h2t[(size_t)(d4 + 1) * NNODES + node] = s1;
            h2t[(size_t)(d4 + 2) * NNODES + node] = s2;
            h2t[(size_t)(d4 + 3) * NNODES + node] = s3;
        } else { s0 = s1 = s2 = s3 = 0.f; }
        float t0 = wave_sum(s0), t1 = wave_sum(s1);
        float t2 = wave_sum(s2), t3 = wave_sum(s3);
        float q0 = wave_sum(s0 * s0), q1 = wave_sum(s1 * s1);
        float q2 = wave_sum(s2 * s2), q3 = wave_sum(s3 * s3);
        if (lane == 0) {
            ws[w][0][d4 + 0] = t0; ws[w][0][d4 + 1] = t1;
            ws[w][0][d4 + 2] = t2; ws[w][0][d4 + 3] = t3;
            ws[w][1][d4 + 0] = q0; ws[w][1][d4 + 1] = q1;
            ws[w][1][d4 + 2] = q2; ws[w][1][d4 + 3] = q3;
        }
    }
    __syncthreads();
    if (threadIdx.x < 128) {
        int which = threadIdx.x >> 6, d = threadIdx.x & 63;
        float s = ws[0][which][d] + ws[1][which][d] + ws[2][which][d] + ws[3][which][d];
        atomicAdd(&stats[which * 64 + d], s);
    }
}

/* bn scale/shift + collapsed key/query vector KQ, qb */
__global__ void k_bnparams(const float* __restrict__ stats, const float* __restrict__ bnw,
                           const float* __restrict__ bnb, const float* __restrict__ keyW,
                           const float* __restrict__ keyB, const float* __restrict__ qw,
                           float* __restrict__ bnp) {
    int d = threadIdx.x;
    float inv_n = 1.0f / (float)NNODES;
    float mu = stats[d] * inv_n;
    float var = stats[64 + d] * inv_n - mu * mu;
    float sc = bnw[d] * rsqrtf(var + 1e-5f);
    bnp[d] = sc;
    bnp[64 + d] = bnb[d] - mu * sc;
    float kq0 = 0.f, kq1 = 0.f;
    #pragma unroll
    for (int j = 0; j < DH; j += 2) {
        kq0 = fmaf(qw[j], keyW[j * DH + d], kq0);
        kq1 = fmaf(qw[j + 1], keyW[(j + 1) * DH + d], kq1);
    }
    bnp[128 + d] = kq0 + kq1;
    float qb = wave_sum(qw[d] * keyB[d]);
    if (d == 0) bnp[192] = qb;
}

/* postA: stream h2_t per-k (coalesced) -> h3[64] (one array); wq; z dots -> z_t bf16 */
__global__ void __launch_bounds__(256, 4)
k_postA(const float* __restrict__ h2t, const float* __restrict__ bnp,
        const float* __restrict__ valW, const float* __restrict__ valB,
        __hip_bfloat16* __restrict__ zt, float* __restrict__ wout) {
    int node = blockIdx.x * 256 + threadIdx.x;
    bool act = node < NNODES;
    int nc = act ? node : 0;
    float h3[DH];
    float p = bnp[192];
    #pragma unroll
    for (int k = 0; k < DH; ++k) {
        float hv = h2t[(size_t)k * NNODES + nc];
        hv = gelu_f(fmaf(hv, bnp[k], bnp[64 + k]));
        h3[k] = hv;
        p = fmaf(hv, bnp[128 + k], p);
    }
    float wq = 1.0f / (1.0f + expf(-p));
    if (act) wout[node] = wq;
    #pragma unroll 1
    for (int d4 = 0; d4 < DH; d4 += 4) {
        float s0 = valB[d4 + 0], s1 = valB[d4 + 1], s2 = valB[d4 + 2], s3 = valB[d4 + 3];
        #pragma unroll
        for (int k = 0; k < DH; ++k) {
            float hk = h3[k];
            s0 = fmaf(valW[(d4 + 0) * DH + k], hk, s0);
            s1 = fmaf(valW[(d4 + 1) * DH + k], hk, s1);
            s2 = fmaf(valW[(d4 + 2) * DH + k], hk, s2);
            s3 = fmaf(valW[(d4 + 3) * DH + k], hk, s3);
        }
        if (act) {
            zt[(size_t)(d4 + 0) * NNODES + node] = __float2bfloat16(s0 * wq);
            zt[(size_t)(d4 + 1) * NNODES + node] = __float2bfloat16(s1 * wq);
            zt[(size_t)(d4 + 2) * NNODES + node] = __float2bfloat16(s2 * wq);
            zt[(size_t)(d4 + 3) * NNODES + node] = __float2bfloat16(s3 * wq);
        }
    }
}

/* postB: z64[64] <- z_t column-row; enc dots -> enc_t bf16; l1 */
__global__ void __launch_bounds__(256, 4)
k_postB(const __hip_bfloat16* __restrict__ zt, const float* __restrict__ encW,
        const float* __restrict__ encB, __hip_bfloat16* __restrict__ enct,
        float* __restrict__ loss) {
    int lane = threadIdx.x & 63;
    int node = blockIdx.x * 256 + threadIdx.x;
    bool act = node < NNODES;
    int nc = act ? node : 0;
    float z64[DH];
    #pragma unroll
    for (int k = 0; k < DH; ++k)
        z64[k] = __bfloat162float(zt[(size_t)k * NNODES + nc]);
    float l1 = 0.f;
    #pragma unroll 1
    for (int d4 = 0; d4 < DH; d4 += 4) {
        float s0 = encB[d4 + 0], s1 = encB[d4 + 1], s2 = encB[d4 + 2], s3 = encB[d4 + 3];
        #pragma unroll
        for (int k = 0; k < DH; ++k) {
            float zk = z64[k];
            s0 = fmaf(encW[(d4 + 0) * DH + k], zk, s0);
            s1 = fmaf(encW[(d4 + 1) * DH + k], zk, s1);
            s2 = fmaf(encW[(d4 + 2) * DH + k], zk, s2);
            s3 = fmaf(encW[(d4 + 3) * DH + k], zk, s3);
        }
        s0 = fmaxf(s0, 0.f); s1 = fmaxf(s1, 0.f);
        s2 = fmaxf(s2, 0.f); s3 = fmaxf(s3, 0.f);
        l1 += (s0 + s1) + (s2 + s3);
        if (act) {
            enct[(size_t)(d4 + 0) * NNODES + node] = __float2bfloat16(s0);
            enct[(size_t)(d4 + 1) * NNODES + node] = __float2bfloat16(s1);
            enct[(size_t)(d4 + 2) * NNODES + node] = __float2bfloat16(s2);
            enct[(size_t)(d4 + 3) * NNODES + node] = __float2bfloat16(s3);
        }
    }
    if (!act) l1 = 0.f;
    l1 = wave_sum(l1);
    if (lane == 0) atomicAdd(&loss[1], l1);
}

/* postC: e64[64] <- enc_t; dec dots; sq vs z_t re-read; dec float4 store [node][dim] */
__global__ void __launch_bounds__(256, 4)
k_postC(const __hip_bfloat16* __restrict__ enct, const __hip_bfloat16* __restrict__ zt,
        const float* __restrict__ decW, const float* __restrict__ decB,
        float* __restrict__ decout, float* __restrict__ loss) {
    int lane = threadIdx.x & 63;
    int node = blockIdx.x * 256 + threadIdx.x;
    bool act = node < NNODES;
    int nc = act ? node : 0;
    float e64[DH];
    #pragma unroll
    for (int k = 0; k < DH; ++k)
        e64[k] = __bfloat162float(enct[(size_t)k * NNODES + nc]);
    float sq = 0.f;
    float* dr = decout + (size_t)nc * DH;
    #pragma unroll 1
    for (int d4 = 0; d4 < DH; d4 += 4) {
        float s0 = decB[d4 + 0], s1 = decB[d4 + 1], s2 = decB[d4 + 2], s3 = decB[d4 + 3];
        #pragma unroll
        for (int k = 0; k < DH; ++k) {
            float ek = e64[k];
            s0 = fmaf(decW[(d4 + 0) * DH + k], ek, s0);
            s1 = fmaf(decW[(d4 + 1) * DH + k], ek, s1);
            s2 = fmaf(decW[(d4 + 2) * DH + k], ek, s2);
            s3 = fmaf(decW[(d4 + 3) * DH + k], ek, s3);
        }
        float z0 = __bfloat162float(zt[(size_t)(d4 + 0) * NNODES + nc]);
        float z1 = __bfloat162float(zt[(size_t)(d4 + 1) * NNODES + nc]);
        float z2 = __bfloat162float(zt[(size_t)(d4 + 2) * NNODES + nc]);
        float z3 = __bfloat162float(zt[(size_t)(d4 + 3) * NNODES + nc]);
        float d0 = s0 - z0, d1 = s1 - z1, d2 = s2 - z2, d3 = s3 - z3;
        sq += (d0 * d0 + d1 * d1) + (d2 * d2 + d3 * d3);
        if (act) {
            float4 v = { s0, s1, s2, s3 };
            *reinterpret_cast<float4*>(dr + d4) = v;
        }
    }
    if (!act) sq = 0.f;
    sq = wave_sum(sq);
    if (lane == 0) atomicAdd(&loss[0], sq);
}

/* g_h[g][d] = sum_{n in graph g} dec[n][d] * w[n]   (wave per chunk, lane = d) */
__global__ void k_ghsum(const float* __restrict__ dec, const float* __restrict__ wout,
                        float* __restrict__ g_h) {
    int lane = threadIdx.x & 63;
    int wid = (blockIdx.x * blockDim.x + threadIdx.x) >> 6;
    int tw = (gridDim.x * blockDim.x) >> 6;
    int chunk = (NNODES + tw - 1) / tw;
    int gs = wid * chunk;
    int ge = min(gs + chunk, NNODES);
    if (gs >= ge) return;
    float gacc = 0.f;
    int cur_g = gs / NGENES;
    for (int n = gs; n < ge; ++n) {
        int g = n / NGENES;
        if (g != cur_g) {
            atomicAdd(&g_h[cur_g * DH + lane], gacc);
            gacc = 0.f;
            cur_g = g;
        }
        gacc = fmaf(dec[(size_t)n * DH + lane], wout[n], gacc);
    }
    atomicAdd(&g_h[cur_g * DH + lane], gacc);
}

/* preds = gelu(g_h@W1.T+b1)@W2.T + b2; sae_loss final */
__global__ void k_pred(const float* __restrict__ g_h, const float* __restrict__ W1,
                       const float* __restrict__ b1, const float* __restrict__ W2,
                       const float* __restrict__ b2, const float* __restrict__ loss,
                       float* __restrict__ out) {
    int lane = threadIdx.x;
    float w1[DH];
    #pragma unroll
    for (int k = 0; k < DH; ++k) w1[k] = W1[lane * DH + k];
    float bb = b1[lane], w2 = W2[lane];
    for (int g = 0; g < BATCH; ++g) {
        float gh = g_h[g * DH + lane];
        float a0 = 0.f, a1 = 0.f;
        #pragma unroll
        for (int k = 0; k < DH; k += 2) {
            a0 = fmaf(w1[k], bcast(gh, k), a0);
            a1 = fmaf(w1[k + 1], bcast(gh, k + 1), a1);
        }
        float t = gelu_f(a0 + a1 + bb);
        float p = wave_sum(t * w2);
        if (lane == 0) out[OUT_PREDS + g] = p + b2[0];
    }
    if (lane == 0) out[OUT_SAE] = (loss[0] + loss[1]) * (1.0f / ((float)NNODES * (float)DH));
}

extern "C" void kernel_launch(void* const* d_in, const int* in_sizes, int n_in,
                              void* d_out, int out_size, void* d_ws, size_t ws_size,
                              hipStream_t stream) {
    const float* x    = (const float*)d_in[0];
    const int* src    = (const int*)d_in[1];
    const int* dst    = (const int*)d_in[2];
    const float* encW = (const float*)d_in[3];
    const float* encB = (const float*)d_in[4];
    const float* gemb = (const float*)d_in[5];
    const float* ginW = (const float*)d_in[6];
    const float* bnw  = (const float*)d_in[7];
    const float* bnb  = (const float*)d_in[8];
    const float* keyW = (const float*)d_in[9];
    const float* keyB = (const float*)d_in[10];
    const float* qw   = (const float*)d_in[11];
    const float* valW = (const float*)d_in[12];
    const float* valB = (const float*)d_in[13];
    const float* saeEncW = (const float*)d_in[14];
    const float* saeEncB = (const float*)d_in[15];
    const float* saeDecW = (const float*)d_in[16];
    const float* saeDecB = (const float*)d_in[17];
    const float* pW1  = (const float*)d_in[18];
    const float* pb1  = (const float*)d_in[19];
    const float* pW2  = (const float*)d_in[20];
    const float* pb2  = (const float*)d_in[21];

    float* out = (float*)d_out;
    float* ws = (float*)d_ws;

    /* ws layout (16B-aligned sections) */
    int*   counts  = (int*)ws;                     /* NNODES */
    float* stats   = ws + NNODES;                  /* 128 */
    float* g_h     = stats + 128;                  /* 512 */
    float* loss    = g_h + 512;                    /* 4 */
    float* bnp     = loss + 4;                     /* 256 */
    int*   offsets = (int*)(bnp + 256);            /* NNODES */
    int*   cursor  = offsets + NNODES;             /* NNODES */
    unsigned short* csr = (unsigned short*)(cursor + NNODES); /* NEDGES u16 */
    int*   bsum    = (int*)(csr + NEDGES);         /* 256 */
    int*   boff    = bsum + 256;                   /* 256 */
    float* h2t     = (float*)(boff + 256);         /* NDH fp32 (later aliased by enc_t) */
    __hip_bfloat16* t = (__hip_bfloat16*)(h2t + NDH); /* NDH bf16 (later aliased by z_t) */

    __hip_bfloat16* zt   = t;                      /* z_t overlays t (t dead after k_gin) */
    __hip_bfloat16* enct = (__hip_bfloat16*)h2t;   /* enc_t overlays h2t (dead after postA) */

    /* h16 (bf16 encoder out) lives in the dec output region until k_postC overwrites it */
    __hip_bfloat16* h16 = (__hip_bfloat16*)(out + OUT_DEC);
    float* decregion = out + OUT_DEC;
    float* wout = out + OUT_W;

    /* zero counts + stats + g_h + loss */
    hipMemsetAsync(d_ws, 0, (size_t)(NNODES + 648) * sizeof(float), stream);

    k_encoder<<<2048, 256, 0, stream>>>(x, encW, encB, gemb, h16);
    k_hist<<<2048, 256, 0, stream>>>(dst, counts);
    k_scan1<<<NSBLK, 256, 0, stream>>>(counts, bsum);
    k_scan2<<<1, 256, 0, stream>>>(bsum, boff);
    k_scan3<<<NSBLK, 256, 0, stream>>>(counts, boff, offsets, cursor);
    k_scatter<<<2048, 256, 0, stream>>>(src, dst, cursor, csr);
    k_agg<<<2048, 256, 0, stream>>>(h16, offsets, counts, csr, t);
    k_gin<<<NBLK_NODE, 256, 0, stream>>>(t, ginW, h2t, stats);
    k_bnparams<<<1, 64, 0, stream>>>(stats, bnw, bnb, keyW, keyB, qw, bnp);
    k_postA<<<NBLK_NODE, 256, 0, stream>>>(h2t, bnp, valW, valB, zt, wout);
    k_postB<<<NBLK_NODE, 256, 0, stream>>>(zt, saeEncW, saeEncB, enct, loss);
    k_postC<<<NBLK_NODE, 256, 0, stream>>>(enct, zt, saeDecW, saeDecB, decregion, loss);
    k_ghsum<<<512, 256, 0, stream>>>(decregion, wout, g_h);
    k_pred<<<1, 64, 0, stream>>>(g_h, pW1, pb1, pW2, pb2, loss, out);
}